// Round 4
// baseline (13347.098 us; speedup 1.0000x reference)
//
#include <hip/hip_runtime.h>

// ---------------------------------------------------------------------------
// mLSTM epitope/antigen model, MI355X fp16-MFMA version, round 4.
//
// R4 changes vs R3 (12.92 ms, regression):
//  - R3's suspected killer: `fa[kb % 3]` buffer rotation needed full unroll
//    of the 60/61-iter K-loop to become static; compiler likely refused ->
//    dynamic local-array indexing -> fragment buffers demoted to scratch.
//    R4 uses chunk-of-4 loop bodies with LITERAL buffer indices (prefetch
//    distance 3, 4 buffers) -- static regardless of unrolling.
//  - Waves halved in rows (stepB 16x(16x4g), stepA 16x32) -> 2x wave count
//    (~1.9 waves/SIMD at t>=25) and lower VGPR pressure (no spill risk).
// ---------------------------------------------------------------------------

typedef _Float16 f16;
typedef _Float16 half8 __attribute__((ext_vector_type(8)));
typedef float f32x4 __attribute__((ext_vector_type(4)));

#define H_    1900
#define HP    1920   // padded hidden
#define KB    1952   // stepB K: 1920 + 10 (x-emb) + 1 (bias) + pad (61*32)
#define NR    512
#define NB_   256
#define TT    153
#define TE    25
#define EMB_  10
#define FCK   3840
#define FCN   384

__device__ __forceinline__ float sigm(float x) {
  float p = __expf(-fabsf(x));
  float r = 1.f / (1.f + p);
  return x >= 0.f ? r : 1.f - r;
}
__device__ __forceinline__ float tanh_(float x) {
  float p = __expf(-2.f * fabsf(x));
  float r = (1.f - p) / (1.f + p);
  return x >= 0.f ? r : -r;
}

// ---------------- prep kernels ----------------

__global__ void k_norms(const float* __restrict__ wh, const float* __restrict__ wx,
                        const float* __restrict__ wmh, const float* __restrict__ wmx,
                        const float* __restrict__ gh, const float* __restrict__ gx,
                        const float* __restrict__ gmh, const float* __restrict__ gmx,
                        float* __restrict__ inv_wh, float* __restrict__ inv_wx,
                        float* __restrict__ inv_wmh, float* __restrict__ inv_wmx) {
  int tid = blockIdx.x * 256 + threadIdx.x;
  if (tid < 7600) {
    float s = 0.f;
    for (int k = 0; k < H_; k++) { float v = wh[(size_t)k * 7600 + tid]; s += v * v; }
    inv_wh[tid] = gh[tid] * rsqrtf(fmaxf(s, 1e-12f));
  } else if (tid < 15200) {
    int n = tid - 7600; float s = 0.f;
    for (int e = 0; e < EMB_; e++) { float v = wx[(size_t)e * 7600 + n]; s += v * v; }
    inv_wx[n] = gx[n] * rsqrtf(fmaxf(s, 1e-12f));
  } else if (tid < 17100) {
    int n = tid - 15200; float s = 0.f;
    for (int k = 0; k < H_; k++) { float v = wmh[(size_t)k * H_ + n]; s += v * v; }
    inv_wmh[n] = gmh[n] * rsqrtf(fmaxf(s, 1e-12f));
  } else if (tid < 19000) {
    int n = tid - 17100; float s = 0.f;
    for (int e = 0; e < EMB_; e++) { float v = wmx[(size_t)e * H_ + n]; s += v * v; }
    inv_wmx[n] = gmx[n] * rsqrtf(fmaxf(s, 1e-12f));
  }
}

// WmhT[n][k] = wmh[k][n]*inv[n], fp16, [1920][1920]
__global__ void k_wmhT(const float* __restrict__ wmh, const float* __restrict__ inv,
                       f16* __restrict__ WmhT) {
  __shared__ float tl[32][33];
  int tx = threadIdx.x, ty = threadIdx.y;
  int kb = blockIdx.y * 32, nb = blockIdx.x * 32;
  #pragma unroll
  for (int i = 0; i < 4; i++) {
    int k = kb + ty + i * 8, n = nb + tx;
    tl[ty + i * 8][tx] = (k < H_ && n < H_) ? wmh[(size_t)k * H_ + n] * inv[n] : 0.f;
  }
  __syncthreads();
  #pragma unroll
  for (int i = 0; i < 4; i++) {
    int n = nb + ty + i * 8, k = kb + tx;
    WmhT[(size_t)n * HP + k] = (f16)tl[tx][ty + i * 8];
  }
}

// WhT[g][n][k]: k<1900 -> wh_n; k in [1920,1930) -> wx_n; k==1930 -> b
__global__ void k_whT(const float* __restrict__ wh, const float* __restrict__ wx,
                      const float* __restrict__ bias,
                      const float* __restrict__ inv_wh, const float* __restrict__ inv_wx,
                      f16* __restrict__ WhT) {
  __shared__ float tl[32][33];
  int tx = threadIdx.x, ty = threadIdx.y;
  int g = blockIdx.z;
  int kb = blockIdx.y * 32, nb = blockIdx.x * 32;
  #pragma unroll
  for (int i = 0; i < 4; i++) {
    int k = kb + ty + i * 8, n = nb + tx;
    float v = 0.f;
    if (n < H_) {
      int col = g * H_ + n;
      if (k < H_)                        v = wh[(size_t)k * 7600 + col] * inv_wh[col];
      else if (k >= HP && k < HP + EMB_) v = wx[(size_t)(k - HP) * 7600 + col] * inv_wx[col];
      else if (k == HP + EMB_)           v = bias[col];
    }
    tl[ty + i * 8][tx] = v;
  }
  __syncthreads();
  #pragma unroll
  for (int i = 0; i < 4; i++) {
    int n = nb + ty + i * 8, k = kb + tx;
    WhT[((size_t)g * HP + n) * KB + k] = (f16)tl[tx][ty + i * 8];
  }
}

// wmxT[n][32]: k<10 -> wmx_n[k][n], else 0  (B operand of the xm-MFMA)
__global__ void k_wmxT(const float* __restrict__ wmx, const float* __restrict__ inv_wmx,
                       f16* __restrict__ wmxT) {
  int i = blockIdx.x * 256 + threadIdx.x;
  if (i >= HP * 32) return;
  int n = i >> 5, k = i & 31;
  float v = (k < EMB_ && n < H_) ? wmx[(size_t)k * H_ + n] * inv_wmx[n] : 0.f;
  wmxT[i] = (f16)v;
}

__global__ void k_lens(const int* __restrict__ ex, const int* __restrict__ lx,
                       const int* __restrict__ rx, int* __restrict__ sel) {
  int s = threadIdx.x;
  int el = 0; for (int i = 0; i < 25; i++) el += (ex[s * 25 + i] != 26);
  int ll = 0; for (int i = 0; i < 64; i++) ll += (lx[s * 64 + i] != 26);
  int rl = 0; for (int i = 0; i < 64; i++) rl += (rx[s * 64 + i] != 26);
  ll = ll < 1 ? 1 : ll;  rl = rl < 1 ? 1 : rl;
  int tl = el + ll + rl;
  int ti = tl - 1; ti = ti < 0 ? 0 : (ti > 152 ? 152 : ti);
  int ei = el - 1; ei = ei < 0 ? 0 : (ei > 24 ? 24 : ei);
  sel[s] = ti; sel[256 + s] = ei;
}

__global__ void k_init(f16* __restrict__ h0, f16* __restrict__ h1, float* __restrict__ c) {
  int i = blockIdx.x * 256 + threadIdx.x;
  if (i < NR * HP) { h0[i] = (f16)0.f; h1[i] = (f16)0.f; c[i] = 0.f; }
}

// xe16[t][row][32]: cols 0..9 = embed[token], col 10 = 1.0 (bias), rest 0
__global__ void k_xe16(const int* __restrict__ totx, const int* __restrict__ epix,
                       const float* __restrict__ embed, f16* __restrict__ xe16) {
  int i = blockIdx.x * blockDim.x + threadIdx.x;
  if (i >= TT * NR) return;
  int t = i / NR, r = i % NR;
  int tok = -1;
  if (r < 256) tok = totx[r * TT + t];
  else if (t < TE) tok = epix[(r - 256) * TE + t];
  f16* o = xe16 + (size_t)i * 32;
  #pragma unroll
  for (int e = 0; e < EMB_; e++) o[e] = (f16)(tok >= 0 ? embed[tok * EMB_ + e] : 0.f);
  o[10] = (f16)1.f;
  #pragma unroll
  for (int e = 11; e < 32; e++) o[e] = (f16)0.f;
}

// ---------------- recurrence kernels (register-direct, static rotation) -----

// Phase A: wave = 16 rows x 32 cols of hm = h @ WmhT (K=1920, 60 iters).
// m = (xe16 @ wmxT) ⊙ hm. Block = 4 row-waves sharing one col-block.
__global__ __launch_bounds__(256)
void k_stepA(const f16* __restrict__ h, const f16* __restrict__ WmhT,
             const f16* __restrict__ xe16_t, const f16* __restrict__ wmxT,
             f16* __restrict__ m) {
  const int lane = threadIdx.x & 63, wid = threadIdx.x >> 6;
  const int col = blockIdx.x % 60, rgrp = blockIdx.x / 60;
  const int r0 = (rgrp * 4 + wid) * 16;
  const int c0 = col * 32;
  const int l16 = lane & 15, l4 = lane >> 4;

  const f16* Abase = h    + (size_t)(r0 + l16) * HP + l4 * 8;
  const f16* Bbase = WmhT + (size_t)(c0 + l16) * HP + l4 * 8;

  // xm = xe16 @ wmxT (one K=32 MFMA per col-frag), C-layout matches hm
  f32x4 xm[2];
  {
    half8 xa = *(const half8*)(xe16_t + (size_t)(r0 + l16) * 32 + l4 * 8);
    #pragma unroll
    for (int cb = 0; cb < 2; cb++) {
      half8 xb = *(const half8*)(wmxT + (size_t)(c0 + cb * 16 + l16) * 32 + l4 * 8);
      f32x4 z = {0.f, 0.f, 0.f, 0.f};
      xm[cb] = __builtin_amdgcn_mfma_f32_16x16x32_f16(xa, xb, z, 0, 0, 0);
    }
  }

  half8 fa0, fa1, fa2, fa3;
  half8 fb0[2], fb1[2], fb2[2], fb3[2];
  f32x4 acc[2];
  #pragma unroll
  for (int cb = 0; cb < 2; cb++) { f32x4 z = {0.f, 0.f, 0.f, 0.f}; acc[cb] = z; }

#define LDA_A(dst, kb)  dst = *(const half8*)(Abase + (size_t)(kb) * 32)
#define LDB_A(dst, kb)  { dst[0] = *(const half8*)(Bbase + (size_t)(kb) * 32); \
                          dst[1] = *(const half8*)(Bbase + (size_t)16 * HP + (size_t)(kb) * 32); }
#define MMA_A(fa, fb) { \
    acc[0] = __builtin_amdgcn_mfma_f32_16x16x32_f16(fa, fb[0], acc[0], 0, 0, 0); \
    acc[1] = __builtin_amdgcn_mfma_f32_16x16x32_f16(fa, fb[1], acc[1], 0, 0, 0); }

  LDA_A(fa0, 0); LDB_A(fb0, 0);
  LDA_A(fa1, 1); LDB_A(fb1, 1);
  LDA_A(fa2, 2); LDB_A(fb2, 2);

  for (int base = 0; base < 60; base += 4) {       // 60 = 4*15, distance 3
    if (base + 3 < 60) { LDA_A(fa3, base + 3); LDB_A(fb3, base + 3); }
    MMA_A(fa0, fb0);
    if (base + 4 < 60) { LDA_A(fa0, base + 4); LDB_A(fb0, base + 4); }
    MMA_A(fa1, fb1);
    if (base + 5 < 60) { LDA_A(fa1, base + 5); LDB_A(fb1, base + 5); }
    MMA_A(fa2, fb2);
    if (base + 6 < 60) { LDA_A(fa2, base + 6); LDB_A(fb2, base + 6); }
    MMA_A(fa3, fb3);
  }
#undef LDA_A
#undef LDB_A
#undef MMA_A

  const int q4 = lane >> 4, c16 = lane & 15;
  #pragma unroll
  for (int cb = 0; cb < 2; cb++)
    #pragma unroll
    for (int q = 0; q < 4; q++) {
      int row = r0 + q4 * 4 + q;
      int cc  = c0 + cb * 16 + c16;
      m[(size_t)row * KB + cc] = (f16)(acc[cb][q] * xm[cb][q]);
    }
  if (col == 0) {  // K-extension tail (cols 1920..1951) = xe16 row
    int row = r0 + (lane >> 2);
    int koff = (lane & 3) * 8;
    *(half8*)(m + (size_t)row * KB + HP + koff) =
        *(const half8*)(xe16_t + (size_t)row * 32 + koff);
  }
}

// Phase B: wave = 16 rows x (16 cols x 4 gates), K=1952 (61 iters) + gates.
// Block = 4 row-waves sharing one col-group (B-frags shared via L1).
__global__ __launch_bounds__(256)
void k_stepB(const f16* __restrict__ m, const f16* __restrict__ WhT,
             float* __restrict__ c, f16* __restrict__ hout,
             float* __restrict__ selH, const int* __restrict__ sel, int t) {
  const int lane = threadIdx.x & 63, wid = threadIdx.x >> 6;
  const int colg = blockIdx.x % 119, rgrp = blockIdx.x / 119;
  const int r0 = (rgrp * 4 + wid) * 16;
  const int c0 = colg * 16;
  const int l16 = lane & 15, l4 = lane >> 4;

  const f16* Abase = m   + (size_t)(r0 + l16) * KB + l4 * 8;
  const f16* Bbase = WhT + (size_t)(c0 + l16) * KB + l4 * 8;

  half8 fa0, fa1, fa2, fa3;
  half8 fb0[4], fb1[4], fb2[4], fb3[4];
  f32x4 acc[4];
  #pragma unroll
  for (int g = 0; g < 4; g++) { f32x4 z = {0.f, 0.f, 0.f, 0.f}; acc[g] = z; }

#define LDA_B(dst, kb)  dst = *(const half8*)(Abase + (size_t)(kb) * 32)
#define LDB_B(dst, kb)  { _Pragma("unroll") \
    for (int gg = 0; gg < 4; gg++) \
      dst[gg] = *(const half8*)(Bbase + (size_t)gg * HP * KB + (size_t)(kb) * 32); }
#define MMA_B(fa, fb) { _Pragma("unroll") \
    for (int gg = 0; gg < 4; gg++) \
      acc[gg] = __builtin_amdgcn_mfma_f32_16x16x32_f16(fa, fb[gg], acc[gg], 0, 0, 0); }

  LDA_B(fa0, 0); LDB_B(fb0, 0);
  LDA_B(fa1, 1); LDB_B(fb1, 1);
  LDA_B(fa2, 2); LDB_B(fb2, 2);

  for (int base = 0; base < 60; base += 4) {       // iters 0..59, distance 3
    if (base + 3 < 61) { LDA_B(fa3, base + 3); LDB_B(fb3, base + 3); }
    MMA_B(fa0, fb0);
    if (base + 4 < 61) { LDA_B(fa0, base + 4); LDB_B(fb0, base + 4); }
    MMA_B(fa1, fb1);
    if (base + 5 < 61) { LDA_B(fa1, base + 5); LDB_B(fb1, base + 5); }
    MMA_B(fa2, fb2);
    if (base + 6 < 61) { LDA_B(fa2, base + 6); LDB_B(fb2, base + 6); }
    MMA_B(fa3, fb3);
  }
  MMA_B(fa0, fb0);                                  // tail iter 60 (60%4==0)
#undef LDA_B
#undef LDB_B
#undef MMA_B

  const int q4 = lane >> 4, c16 = lane & 15;
  const int j = c0 + c16;
  const bool valid = j < H_;
  #pragma unroll
  for (int q = 0; q < 4; q++) {
    int row = r0 + q4 * 4 + q;
    size_t idx = (size_t)row * HP + j;
    if (valid) {
      float cold = c[idx];
      float iz = acc[0][q], fz = acc[1][q];
      float oz = acc[2][q], uz = acc[3][q];
      float cn = sigm(fz) * cold + sigm(iz) * tanh_(uz);
      float hv = sigm(oz) * tanh_(cn);
      c[idx] = cn;
      hout[idx] = (f16)hv;
      if (t == sel[row]) selH[idx] = hv;
    } else {
      c[idx] = 0.f; hout[idx] = (f16)0.f;
    }
  }
}

// ---------------- classifier ----------------

__global__ void k_xq(const float* __restrict__ selH, const float* __restrict__ g1,
                     const float* __restrict__ be1, const float* __restrict__ mu1,
                     const float* __restrict__ var1, f16* __restrict__ xq) {
  int i = blockIdx.x * 256 + threadIdx.x;
  if (i >= 256 * FCK) return;
  int s = i / FCK, k = i % FCK;
  float v = 0.f;
  if (k < H_)          v = selH[(size_t)s * HP + k];
  else if (k < 2 * H_) v = selH[(size_t)(256 + s) * HP + (k - H_)];
  float lr = v < 0.f ? 0.3f * v : v;
  float q = 0.f;
  if (k < 2 * H_) q = (lr - mu1[k]) * rsqrtf(var1[k] + 1e-3f) * g1[k] + be1[k];
  xq[i] = (f16)q;
}

__global__ void k_w1t(const float* __restrict__ W1, f16* __restrict__ W1T) {
  int i = blockIdx.x * 256 + threadIdx.x;
  if (i >= FCN * FCK) return;
  int cidx = i / FCK, k = i % FCK;
  W1T[i] = (f16)((cidx < 380 && k < 2 * H_) ? W1[(size_t)k * 380 + cidx] : 0.f);
}

// fc1: register-direct, wave = 16 rows x 64 cols, K=3840 (120 iters).
// grid = (256/16 rows) x (384/64 cols) = 16 x 6 waves, 1 wave/block of 64.
__global__ __launch_bounds__(64)
void k_fc1(const f16* __restrict__ xq, const f16* __restrict__ W1T,
           const float* __restrict__ b1, float* __restrict__ z1) {
  const int lane = threadIdx.x;
  const int r0 = (int)blockIdx.y * 16, c0 = (int)blockIdx.x * 64;
  const int l16 = lane & 15, l4 = lane >> 4;

  const f16* Abase = xq  + (size_t)(r0 + l16) * FCK + l4 * 8;
  const f16* Bbase = W1T + (size_t)(c0 + l16) * FCK + l4 * 8;

  half8 fa0, fa1, fa2, fa3;
  half8 fb0[4], fb1[4], fb2[4], fb3[4];
  f32x4 acc[4];
  #pragma unroll
  for (int cb = 0; cb < 4; cb++) { f32x4 z = {0.f, 0.f, 0.f, 0.f}; acc[cb] = z; }

#define LDA_F(dst, kb)  dst = *(const half8*)(Abase + (size_t)(kb) * 32)
#define LDB_F(dst, kb)  { _Pragma("unroll") \
    for (int cb = 0; cb < 4; cb++) \
      dst[cb] = *(const half8*)(Bbase + (size_t)cb * 16 * FCK + (size_t)(kb) * 32); }
#define MMA_F(fa, fb) { _Pragma("unroll") \
    for (int cb = 0; cb < 4; cb++) \
      acc[cb] = __builtin_amdgcn_mfma_f32_16x16x32_f16(fa, fb[cb], acc[cb], 0, 0, 0); }

  LDA_F(fa0, 0); LDB_F(fb0, 0);
  LDA_F(fa1, 1); LDB_F(fb1, 1);
  LDA_F(fa2, 2); LDB_F(fb2, 2);

  for (int base = 0; base < 120; base += 4) {      // 120 = 4*30
    if (base + 3 < 120) { LDA_F(fa3, base + 3); LDB_F(fb3, base + 3); }
    MMA_F(fa0, fb0);
    if (base + 4 < 120) { LDA_F(fa0, base + 4); LDB_F(fb0, base + 4); }
    MMA_F(fa1, fb1);
    if (base + 5 < 120) { LDA_F(fa1, base + 5); LDB_F(fb1, base + 5); }
    MMA_F(fa2, fb2);
    if (base + 6 < 120) { LDA_F(fa2, base + 6); LDB_F(fb2, base + 6); }
    MMA_F(fa3, fb3);
  }
#undef LDA_F
#undef LDB_F
#undef MMA_F

  const int q4 = lane >> 4, c16 = lane & 15;
  #pragma unroll
  for (int cb = 0; cb < 4; cb++)
    #pragma unroll
    for (int q = 0; q < 4; q++) {
      int rl = r0 + q4 * 4 + q;
      int col = c0 + cb * 16 + c16;
      float bias = (col < 380) ? b1[col] : 0.f;
      z1[(size_t)rl * FCN + col] = acc[cb][q] + bias;
    }
}

__global__ void k_fc2(const float* __restrict__ z1, const float* __restrict__ g2,
                      const float* __restrict__ be2, const float* __restrict__ mu2,
                      const float* __restrict__ var2, const float* __restrict__ W2,
                      const float* __restrict__ b2, float* __restrict__ out) {
  int s = threadIdx.x;
  float a = 0.f;
  for (int jj = 0; jj < 380; jj++) {
    float v = z1[(size_t)s * FCN + jj];
    float lr = v < 0.f ? 0.3f * v : v;
    float q = (lr - mu2[jj]) * rsqrtf(var2[jj] + 1e-3f) * g2[jj] + be2[jj];
    a += q * W2[jj];
  }
  out[s] = a + b2[0];
}

// ---------------- host ----------------

extern "C" void kernel_launch(void* const* d_in, const int* in_sizes, int n_in,
                              void* d_out, int out_size, void* d_ws, size_t ws_size,
                              hipStream_t stream) {
  const int*   epix  = (const int*)d_in[0];
  const int*   lx    = (const int*)d_in[1];
  const int*   rx    = (const int*)d_in[2];
  const int*   totx  = (const int*)d_in[3];
  const float* embed = (const float*)d_in[4];
  const float* wx    = (const float*)d_in[5];
  const float* wh    = (const float*)d_in[6];
  const float* wmx   = (const float*)d_in[7];
  const float* wmh   = (const float*)d_in[8];
  const float* bb    = (const float*)d_in[9];
  const float* gx    = (const float*)d_in[10];
  const float* gh    = (const float*)d_in[11];
  const float* gmx   = (const float*)d_in[12];
  const float* gmh   = (const float*)d_in[13];
  const float* bn1g  = (const float*)d_in[14];
  const float* bn1b  = (const float*)d_in[15];
  const float* bn1m  = (const float*)d_in[16];
  const float* bn1v  = (const float*)d_in[17];
  const float* W1    = (const float*)d_in[18];
  const float* b1    = (const float*)d_in[19];
  const float* bn2g  = (const float*)d_in[20];
  const float* bn2b  = (const float*)d_in[21];
  const float* bn2m  = (const float*)d_in[22];
  const float* bn2v  = (const float*)d_in[23];
  const float* W2    = (const float*)d_in[24];
  const float* b2v   = (const float*)d_in[25];

  char* base = (char*)d_ws;
  size_t off = 0;
  auto alloc = [&](size_t n) { char* p = base + off; off = (off + n + 255) & ~(size_t)255; return p; };

  f16*   WmhT   = (f16*)  alloc((size_t)HP * HP * 2);
  f16*   WhT    = (f16*)  alloc((size_t)4 * HP * KB * 2);
  f16*   wmxT   = (f16*)  alloc((size_t)HP * 32 * 2);
  f16*   xe16   = (f16*)  alloc((size_t)TT * NR * 32 * 2);
  f16*   h0     = (f16*)  alloc((size_t)NR * HP * 2);
  f16*   h1     = (f16*)  alloc((size_t)NR * HP * 2);
  f16*   mbuf   = (f16*)  alloc((size_t)NR * KB * 2);
  float* cst    = (float*)alloc((size_t)NR * HP * 4);
  float* selH   = (float*)alloc((size_t)NR * HP * 4);
  int*   sel    = (int*)  alloc((size_t)NR * 4);
  float* inv_wh = (float*)alloc(7600 * 4);
  float* inv_wx = (float*)alloc(7600 * 4);
  float* inv_wmh= (float*)alloc(1900 * 4);
  float* inv_wmx= (float*)alloc(1900 * 4);
  f16*   xq     = (f16*)  alloc((size_t)256 * FCK * 2);
  f16*   W1T    = (f16*)  alloc((size_t)FCN * FCK * 2);
  float* z1     = (float*)alloc((size_t)256 * FCN * 4);
  (void)in_sizes; (void)n_in; (void)out_size; (void)ws_size;

  hipLaunchKernelGGL(k_norms, dim3(75), dim3(256), 0, stream,
                     wh, wx, wmh, wmx, gh, gx, gmh, gmx, inv_wh, inv_wx, inv_wmh, inv_wmx);
  hipLaunchKernelGGL(k_wmhT, dim3(60, 60), dim3(32, 8), 0, stream, wmh, inv_wmh, WmhT);
  hipLaunchKernelGGL(k_whT, dim3(60, 61, 4), dim3(32, 8), 0, stream,
                     wh, wx, bb, inv_wh, inv_wx, WhT);
  hipLaunchKernelGGL(k_wmxT, dim3((HP * 32 + 255) / 256), dim3(256), 0, stream,
                     wmx, inv_wmx, wmxT);
  hipLaunchKernelGGL(k_lens, dim3(1), dim3(256), 0, stream, epix, lx, rx, sel);
  hipLaunchKernelGGL(k_init, dim3((NR * HP + 255) / 256), dim3(256), 0, stream, h0, h1, cst);
  hipLaunchKernelGGL(k_xe16, dim3((TT * NR + 255) / 256), dim3(256), 0, stream,
                     totx, epix, embed, xe16);

  for (int t = 0; t < TT; t++) {
    int Mt = (t < TE) ? NR : NB_;
    const f16* hin = (t & 1) ? h1 : h0;
    f16*       ho  = (t & 1) ? h0 : h1;
    int rg = Mt / 64;  // row-groups of 64 (4 waves x 16 rows)
    hipLaunchKernelGGL(k_stepA, dim3(60 * rg), dim3(256), 0, stream,
                       hin, WmhT, xe16 + (size_t)t * NR * 32, wmxT, mbuf);
    hipLaunchKernelGGL(k_stepB, dim3(119 * rg), dim3(256), 0, stream,
                       mbuf, WhT, cst, ho, selH, sel, t);
  }

  hipLaunchKernelGGL(k_xq, dim3((256 * FCK + 255) / 256), dim3(256), 0, stream,
                     selH, bn1g, bn1b, bn1m, bn1v, xq);
  hipLaunchKernelGGL(k_w1t, dim3((FCN * FCK + 255) / 256), dim3(256), 0, stream, W1, W1T);
  hipLaunchKernelGGL(k_fc1, dim3(6, 16), dim3(64), 0, stream, xq, W1T, b1, z1);
  hipLaunchKernelGGL(k_fc2, dim3(1), dim3(256), 0, stream,
                     z1, bn2g, bn2b, bn2m, bn2v, W2, b2v, (float*)d_out);
}

// Round 5
// 7798.039 us; speedup vs baseline: 1.7116x; 1.7116x over previous
//
#include <hip/hip_runtime.h>

// ---------------------------------------------------------------------------
// mLSTM epitope/antigen model, MI355X fp16-MFMA, round 5.
//
// R5 vs R4 (13.3 ms): every K-loop operand is PRE-SWIZZLED into MFMA
// fragment order [tile][kchunk][lane][8], so each fragment load is one
// contiguous 1 KB global_load_dwordx4 per wave (R3/R4 loaded 16 scattered
// 64B segments per instruction -> TA/address-pipe bound). No LDS anywhere
// in hot loops (avoids R2's LDS-DMA barrier drains). Static 4-deep
// register prefetch rotation (R4 pattern).
//   stepA: wave 16 rows x 64 cols, K=1920 (60 ch); m written swizzled.
//   stepB: wave 32 rows x (16 cols x 4 gates), K=1952 (61 ch), 2 row-groups
//          -> WhS streamed only 2x/step; h written swizzled for next stepA.
// ---------------------------------------------------------------------------

typedef _Float16 f16;
typedef _Float16 half8 __attribute__((ext_vector_type(8)));
typedef float f32x4 __attribute__((ext_vector_type(4)));

#define H_    1900
#define HP    1920
#define NKA   60     // K-chunks for h/WmhS (1920/32)
#define NKB   61     // K-chunks for m/WhS (1952/32)
#define NKF   120    // K-chunks for fc1 (3840/32)
#define NR    512
#define TT    153
#define TE    25
#define EMB_  10
#define FCN   384

__device__ __forceinline__ float sigm(float x) {
  float p = __expf(-fabsf(x));
  float r = 1.f / (1.f + p);
  return x >= 0.f ? r : 1.f - r;
}
__device__ __forceinline__ float tanh_(float x) {
  float p = __expf(-2.f * fabsf(x));
  float r = (1.f - p) / (1.f + p);
  return x >= 0.f ? r : -r;
}

// ---------------- prep ----------------

__global__ void k_norms(const float* __restrict__ wh, const float* __restrict__ wx,
                        const float* __restrict__ wmh, const float* __restrict__ wmx,
                        const float* __restrict__ gh, const float* __restrict__ gx,
                        const float* __restrict__ gmh, const float* __restrict__ gmx,
                        float* __restrict__ inv_wh, float* __restrict__ inv_wx,
                        float* __restrict__ inv_wmh, float* __restrict__ inv_wmx) {
  int tid = blockIdx.x * 256 + threadIdx.x;
  if (tid < 7600) {
    float s = 0.f;
    for (int k = 0; k < H_; k++) { float v = wh[(size_t)k * 7600 + tid]; s += v * v; }
    inv_wh[tid] = gh[tid] * rsqrtf(fmaxf(s, 1e-12f));
  } else if (tid < 15200) {
    int n = tid - 7600; float s = 0.f;
    for (int e = 0; e < EMB_; e++) { float v = wx[(size_t)e * 7600 + n]; s += v * v; }
    inv_wx[n] = gx[n] * rsqrtf(fmaxf(s, 1e-12f));
  } else if (tid < 17100) {
    int n = tid - 15200; float s = 0.f;
    for (int k = 0; k < H_; k++) { float v = wmh[(size_t)k * H_ + n]; s += v * v; }
    inv_wmh[n] = gmh[n] * rsqrtf(fmaxf(s, 1e-12f));
  } else if (tid < 19000) {
    int n = tid - 17100; float s = 0.f;
    for (int e = 0; e < EMB_; e++) { float v = wmx[(size_t)e * H_ + n]; s += v * v; }
    inv_wmx[n] = gmx[n] * rsqrtf(fmaxf(s, 1e-12f));
  }
}

// WmhS fragment-swizzled: group (c,kb): element (n=16c+nl, k=32kb+kl)
__global__ void k_wmhS(const float* __restrict__ wmh, const float* __restrict__ inv,
                       f16* __restrict__ WmhS) {
  int i = blockIdx.x * 256 + threadIdx.x;
  if (i >= 1920 * 1920) return;
  int n = i % 1920, k = i / 1920;
  float v = (n < H_ && k < H_) ? wmh[(size_t)k * H_ + n] * inv[n] : 0.f;
  int c = n >> 4, nl = n & 15, kb = k >> 5, kl = k & 31;
  WmhS[(((size_t)c * NKA + kb) * 512) + (nl + 16 * (kl >> 3)) * 8 + (kl & 7)] = (f16)v;
}

// WhS fragment-swizzled, gate-grouped: group (q*4+g, kb); K-ext rows carry wx/b
__global__ void k_whS(const float* __restrict__ wh, const float* __restrict__ wx,
                      const float* __restrict__ bias,
                      const float* __restrict__ inv_wh, const float* __restrict__ inv_wx,
                      f16* __restrict__ WhS) {
  int i = blockIdx.x * 256 + threadIdx.x;
  if (i >= 7600 * 1952) return;
  int col = i % 7600, k = i / 7600;
  float v = 0.f;
  if (k < H_)                        v = wh[(size_t)k * 7600 + col] * inv_wh[col];
  else if (k >= HP && k < HP + EMB_) v = wx[(size_t)(k - HP) * 7600 + col] * inv_wx[col];
  else if (k == HP + EMB_)           v = bias[col];
  int g = col / H_, n = col % H_;
  int q = n >> 4, nl = n & 15, kb = k >> 5, kl = k & 31;
  WhS[(((size_t)(q * 4 + g) * NKB + kb) * 512) + (nl + 16 * (kl >> 3)) * 8 + (kl & 7)] = (f16)v;
}

// wmxT[n][32] (strided frag, read once per wave - ok)
__global__ void k_wmxT(const float* __restrict__ wmx, const float* __restrict__ inv_wmx,
                       f16* __restrict__ wmxT) {
  int i = blockIdx.x * 256 + threadIdx.x;
  if (i >= HP * 32) return;
  int n = i >> 5, k = i & 31;
  float v = (k < EMB_ && n < H_) ? wmx[(size_t)k * H_ + n] * inv_wmx[n] : 0.f;
  wmxT[i] = (f16)v;
}

__global__ void k_lens(const int* __restrict__ ex, const int* __restrict__ lx,
                       const int* __restrict__ rx, int* __restrict__ sel) {
  int s = threadIdx.x;
  int el = 0; for (int i = 0; i < 25; i++) el += (ex[s * 25 + i] != 26);
  int ll = 0; for (int i = 0; i < 64; i++) ll += (lx[s * 64 + i] != 26);
  int rl = 0; for (int i = 0; i < 64; i++) rl += (rx[s * 64 + i] != 26);
  ll = ll < 1 ? 1 : ll;  rl = rl < 1 ? 1 : rl;
  int tl = el + ll + rl;
  int ti = tl - 1; ti = ti < 0 ? 0 : (ti > 152 ? 152 : ti);
  int ei = el - 1; ei = ei < 0 ? 0 : (ei > 24 ? 24 : ei);
  sel[s] = ti; sel[256 + s] = ei;
}

__global__ void k_init(f16* __restrict__ h0, f16* __restrict__ h1, float* __restrict__ c) {
  int i = blockIdx.x * 256 + threadIdx.x;
  if (i < NR * HP) { h0[i] = (f16)0.f; h1[i] = (f16)0.f; c[i] = 0.f; }
}

// xe16[t][row][32]: cols 0..9 = embed[token], col 10 = 1.0 (bias), rest 0
__global__ void k_xe16(const int* __restrict__ totx, const int* __restrict__ epix,
                       const float* __restrict__ embed, f16* __restrict__ xe16) {
  int i = blockIdx.x * blockDim.x + threadIdx.x;
  if (i >= TT * NR) return;
  int t = i / NR, r = i % NR;
  int tok = -1;
  if (r < 256) tok = totx[r * TT + t];
  else if (t < TE) tok = epix[(r - 256) * TE + t];
  f16* o = xe16 + (size_t)i * 32;
  #pragma unroll
  for (int e = 0; e < EMB_; e++) o[e] = (f16)(tok >= 0 ? embed[tok * EMB_ + e] : 0.f);
  o[10] = (f16)1.f;
  #pragma unroll
  for (int e = 11; e < 32; e++) o[e] = (f16)0.f;
}

// ---------------- recurrence ----------------

// Phase A: wave = 16 rows x 64 cols; all loads contiguous 1KB fragments.
__global__ __launch_bounds__(256)
void k_stepA(const f16* __restrict__ hS, const f16* __restrict__ WmhS,
             const f16* __restrict__ xe16_t, const f16* __restrict__ wmxT,
             f16* __restrict__ mS) {
  const int lane = threadIdx.x & 63, wid = threadIdx.x >> 6;
  const int ct = blockIdx.x % 30, rg = blockIdx.x / 30;
  const int rtile = rg * 4 + wid;
  const int r0 = rtile * 16;
  const int l16 = lane & 15, l4 = lane >> 4;

  const f16* Abase = hS   + (size_t)rtile * NKA * 512 + lane * 8;
  const f16* Bbase = WmhS + (size_t)(ct * 4) * NKA * 512 + lane * 8;

  // xm = xe16 @ wmxT (once; strided frags are fine here)
  f32x4 xm[4];
  {
    half8 xa = *(const half8*)(xe16_t + (size_t)(r0 + l16) * 32 + l4 * 8);
    #pragma unroll
    for (int cb = 0; cb < 4; cb++) {
      half8 xb = *(const half8*)(wmxT + (size_t)(ct * 64 + cb * 16 + l16) * 32 + l4 * 8);
      f32x4 z = {0.f, 0.f, 0.f, 0.f};
      xm[cb] = __builtin_amdgcn_mfma_f32_16x16x32_f16(xa, xb, z, 0, 0, 0);
    }
  }

  half8 fa0, fa1, fa2, fa3;
  half8 fb0[4], fb1[4], fb2[4], fb3[4];
  f32x4 acc[4];
  #pragma unroll
  for (int cb = 0; cb < 4; cb++) { f32x4 z = {0.f, 0.f, 0.f, 0.f}; acc[cb] = z; }

#define LDA_A(d, kb)  d = *(const half8*)(Abase + (size_t)(kb) * 512)
#define LDB_A(d, kb)  { _Pragma("unroll") for (int cb = 0; cb < 4; cb++) \
    d[cb] = *(const half8*)(Bbase + ((size_t)cb * NKA + (kb)) * 512); }
#define MMA_A(fa, fb) { _Pragma("unroll") for (int cb = 0; cb < 4; cb++) \
    acc[cb] = __builtin_amdgcn_mfma_f32_16x16x32_f16(fa, fb[cb], acc[cb], 0, 0, 0); }

  LDA_A(fa0, 0); LDB_A(fb0, 0);
  LDA_A(fa1, 1); LDB_A(fb1, 1);
  LDA_A(fa2, 2); LDB_A(fb2, 2);
  for (int base = 0; base < 60; base += 4) {
    if (base + 3 < 60) { LDA_A(fa3, base + 3); LDB_A(fb3, base + 3); }
    MMA_A(fa0, fb0);
    if (base + 4 < 60) { LDA_A(fa0, base + 4); LDB_A(fb0, base + 4); }
    MMA_A(fa1, fb1);
    if (base + 5 < 60) { LDA_A(fa1, base + 5); LDB_A(fb1, base + 5); }
    MMA_A(fa2, fb2);
    if (base + 6 < 60) { LDA_A(fa2, base + 6); LDB_A(fb2, base + 6); }
    MMA_A(fa3, fb3);
  }
#undef LDA_A
#undef LDB_A
#undef MMA_A

  // epilogue: m = hm * xm, written in stepB's A-fragment order
  const int q4 = lane >> 4, c16 = lane & 15;
  #pragma unroll
  for (int cb = 0; cb < 4; cb++) {
    int kb = ct * 2 + (cb >> 1);
    int klane = (cb & 1) * 16 + c16;          // k & 31
    int lf = (klane >> 3) * 16;               // 16*((k>>3)&3)
    int sub = c16 & 7;
    f16* dst = mS + ((size_t)rtile * NKB + kb) * 512 + sub;
    #pragma unroll
    for (int q = 0; q < 4; q++) {
      int rl = q4 * 4 + q;
      dst[(rl + lf) * 8] = (f16)(acc[cb][q] * xm[cb][q]);
    }
  }
  if (ct == 0) {  // K-extension chunk 60 = xe16 row (contiguous copy)
    f16* dst = mS + ((size_t)rtile * NKB + 60) * 512 + lane * 8;
    *(half8*)dst = *(const half8*)(xe16_t + (size_t)(r0 + l16) * 32 + l4 * 8);
  }
}

// Phase B: wave = 32 rows x (16 cols x 4 gates); 2 row-groups per step (t>=25).
__global__ __launch_bounds__(256)
void k_stepB(const f16* __restrict__ mS, const f16* __restrict__ WhS,
             float* __restrict__ c, f16* __restrict__ houtS,
             float* __restrict__ selH, const int* __restrict__ sel, int t) {
  const int lane = threadIdx.x & 63, wid = threadIdx.x >> 6;
  const int colq = blockIdx.x % 119, rg = blockIdx.x / 119;
  const int rt0 = (rg * 4 + wid) * 2;   // first 16-row tile of this wave
  const int r0 = rt0 * 16;

  const f16* Abase = mS  + (size_t)rt0 * NKB * 512 + lane * 8;
  const f16* Bbase = WhS + (size_t)(colq * 4) * NKB * 512 + lane * 8;

  half8 fa0[2], fa1[2], fa2[2], fa3[2];
  half8 fb0[4], fb1[4], fb2[4], fb3[4];
  f32x4 acc[2][4];
  #pragma unroll
  for (int a = 0; a < 2; a++)
    #pragma unroll
    for (int b = 0; b < 4; b++) { f32x4 z = {0.f, 0.f, 0.f, 0.f}; acc[a][b] = z; }

#define LDA_B(d, kb)  { _Pragma("unroll") for (int rf = 0; rf < 2; rf++) \
    d[rf] = *(const half8*)(Abase + ((size_t)rf * NKB + (kb)) * 512); }
#define LDB_B(d, kb)  { _Pragma("unroll") for (int gg = 0; gg < 4; gg++) \
    d[gg] = *(const half8*)(Bbase + ((size_t)gg * NKB + (kb)) * 512); }
#define MMA_B(fa, fb) { _Pragma("unroll") for (int rf = 0; rf < 2; rf++) \
    { _Pragma("unroll") for (int gg = 0; gg < 4; gg++) \
      acc[rf][gg] = __builtin_amdgcn_mfma_f32_16x16x32_f16(fa[rf], fb[gg], acc[rf][gg], 0, 0, 0); } }

  LDA_B(fa0, 0); LDB_B(fb0, 0);
  LDA_B(fa1, 1); LDB_B(fb1, 1);
  LDA_B(fa2, 2); LDB_B(fb2, 2);
  for (int base = 0; base < 60; base += 4) {
    if (base + 3 < 61) { LDA_B(fa3, base + 3); LDB_B(fb3, base + 3); }
    MMA_B(fa0, fb0);
    if (base + 4 < 61) { LDA_B(fa0, base + 4); LDB_B(fb0, base + 4); }
    MMA_B(fa1, fb1);
    if (base + 5 < 61) { LDA_B(fa1, base + 5); LDB_B(fb1, base + 5); }
    MMA_B(fa2, fb2);
    if (base + 6 < 61) { LDA_B(fa2, base + 6); LDB_B(fb2, base + 6); }
    MMA_B(fa3, fb3);
  }
  MMA_B(fa0, fb0);   // chunk 60
#undef LDA_B
#undef LDB_B
#undef MMA_B

  const int q4 = lane >> 4, c16 = lane & 15;
  const int j = colq * 16 + c16;
  const bool valid = j < H_;
  const int kbh = colq >> 1;
  const int lfh = ((((colq & 1) * 16 + c16) >> 3)) * 16;
  const int subh = c16 & 7;
  #pragma unroll
  for (int rf = 0; rf < 2; rf++) {
    f16* hdst = houtS + ((size_t)(rt0 + rf) * NKA + kbh) * 512 + subh;
    #pragma unroll
    for (int q = 0; q < 4; q++) {
      int rl = q4 * 4 + q;
      int row = r0 + rf * 16 + rl;
      if (valid) {
        size_t idx = (size_t)row * HP + j;
        float cold = c[idx];
        float iz = acc[rf][0][q], fz = acc[rf][1][q];
        float oz = acc[rf][2][q], uz = acc[rf][3][q];
        float cn = sigm(fz) * cold + sigm(iz) * tanh_(uz);
        float hv = sigm(oz) * tanh_(cn);
        c[idx] = cn;
        hdst[(rl + lfh) * 8] = (f16)hv;
        if (t == sel[row]) selH[idx] = hv;
      }
    }
  }
}

// ---------------- classifier ----------------

// xq in fragment order (reads selH coalesced)
__global__ void k_xqS(const float* __restrict__ selH, const float* __restrict__ g1,
                      const float* __restrict__ be1, const float* __restrict__ mu1,
                      const float* __restrict__ var1, f16* __restrict__ xqS) {
  int i = blockIdx.x * 256 + threadIdx.x;
  if (i >= 256 * 3840) return;
  int k = i % 3840, s = i / 3840;
  float v = 0.f; bool have = false;
  if (k < H_)            { v = selH[(size_t)s * HP + k]; have = true; }
  else if (k < 2 * H_)   { v = selH[(size_t)(256 + s) * HP + (k - H_)]; have = true; }
  float q = 0.f;
  if (have) {
    float lr = v < 0.f ? 0.3f * v : v;
    q = (lr - mu1[k]) * rsqrtf(var1[k] + 1e-3f) * g1[k] + be1[k];
  }
  int rtile = s >> 4, sl = s & 15, kb = k >> 5, kl = k & 31;
  xqS[(((size_t)rtile * NKF + kb) * 512) + (sl + 16 * (kl >> 3)) * 8 + (kl & 7)] = (f16)q;
}

__global__ void k_w1S(const float* __restrict__ W1, f16* __restrict__ W1S) {
  int i = blockIdx.x * 256 + threadIdx.x;
  if (i >= 384 * 3840) return;
  int col = i % 384, k = i / 384;
  float v = (col < 380 && k < 2 * H_) ? W1[(size_t)k * 380 + col] : 0.f;
  int cg = col >> 4, nl = col & 15, kb = k >> 5, kl = k & 31;
  W1S[(((size_t)cg * NKF + kb) * 512) + (nl + 16 * (kl >> 3)) * 8 + (kl & 7)] = (f16)v;
}

// fc1: wave = 16 rows x 64 cols, K=3840 (120 chunks), contiguous frags
__global__ __launch_bounds__(256)
void k_fc1(const f16* __restrict__ xqS, const f16* __restrict__ W1S,
           const float* __restrict__ b1, float* __restrict__ z1) {
  const int lane = threadIdx.x & 63, wid = threadIdx.x >> 6;
  const int ct = blockIdx.x % 6, rg = blockIdx.x / 6;
  const int rtile = rg * 4 + wid;
  const int r0 = rtile * 16;

  const f16* Abase = xqS + (size_t)rtile * NKF * 512 + lane * 8;
  const f16* Bbase = W1S + (size_t)(ct * 4) * NKF * 512 + lane * 8;

  half8 fa0, fa1, fa2, fa3;
  half8 fb0[4], fb1[4], fb2[4], fb3[4];
  f32x4 acc[4];
  #pragma unroll
  for (int cb = 0; cb < 4; cb++) { f32x4 z = {0.f, 0.f, 0.f, 0.f}; acc[cb] = z; }

#define LDA_F(d, kb)  d = *(const half8*)(Abase + (size_t)(kb) * 512)
#define LDB_F(d, kb)  { _Pragma("unroll") for (int cb = 0; cb < 4; cb++) \
    d[cb] = *(const half8*)(Bbase + ((size_t)cb * NKF + (kb)) * 512); }
#define MMA_F(fa, fb) { _Pragma("unroll") for (int cb = 0; cb < 4; cb++) \
    acc[cb] = __builtin_amdgcn_mfma_f32_16x16x32_f16(fa, fb[cb], acc[cb], 0, 0, 0); }

  LDA_F(fa0, 0); LDB_F(fb0, 0);
  LDA_F(fa1, 1); LDB_F(fb1, 1);
  LDA_F(fa2, 2); LDB_F(fb2, 2);
  for (int base = 0; base < 120; base += 4) {
    if (base + 3 < 120) { LDA_F(fa3, base + 3); LDB_F(fb3, base + 3); }
    MMA_F(fa0, fb0);
    if (base + 4 < 120) { LDA_F(fa0, base + 4); LDB_F(fb0, base + 4); }
    MMA_F(fa1, fb1);
    if (base + 5 < 120) { LDA_F(fa1, base + 5); LDB_F(fb1, base + 5); }
    MMA_F(fa2, fb2);
    if (base + 6 < 120) { LDA_F(fa2, base + 6); LDB_F(fb2, base + 6); }
    MMA_F(fa3, fb3);
  }
#undef LDA_F
#undef LDB_F
#undef MMA_F

  const int q4 = lane >> 4, c16 = lane & 15;
  #pragma unroll
  for (int cb = 0; cb < 4; cb++)
    #pragma unroll
    for (int q = 0; q < 4; q++) {
      int row = r0 + q4 * 4 + q;
      int col = ct * 64 + cb * 16 + c16;
      float bias = (col < 380) ? b1[col] : 0.f;
      z1[(size_t)row * FCN + col] = acc[cb][q] + bias;
    }
}

__global__ void k_fc2(const float* __restrict__ z1, const float* __restrict__ g2,
                      const float* __restrict__ be2, const float* __restrict__ mu2,
                      const float* __restrict__ var2, const float* __restrict__ W2,
                      const float* __restrict__ b2, float* __restrict__ out) {
  int s = threadIdx.x;
  float a = 0.f;
  for (int jj = 0; jj < 380; jj++) {
    float v = z1[(size_t)s * FCN + jj];
    float lr = v < 0.f ? 0.3f * v : v;
    float q = (lr - mu2[jj]) * rsqrtf(var2[jj] + 1e-3f) * g2[jj] + be2[jj];
    a += q * W2[jj];
  }
  out[s] = a + b2[0];
}

// ---------------- host ----------------

extern "C" void kernel_launch(void* const* d_in, const int* in_sizes, int n_in,
                              void* d_out, int out_size, void* d_ws, size_t ws_size,
                              hipStream_t stream) {
  const int*   epix  = (const int*)d_in[0];
  const int*   lx    = (const int*)d_in[1];
  const int*   rx    = (const int*)d_in[2];
  const int*   totx  = (const int*)d_in[3];
  const float* embed = (const float*)d_in[4];
  const float* wx    = (const float*)d_in[5];
  const float* wh    = (const float*)d_in[6];
  const float* wmx   = (const float*)d_in[7];
  const float* wmh   = (const float*)d_in[8];
  const float* bb    = (const float*)d_in[9];
  const float* gx    = (const float*)d_in[10];
  const float* gh    = (const float*)d_in[11];
  const float* gmx   = (const float*)d_in[12];
  const float* gmh   = (const float*)d_in[13];
  const float* bn1g  = (const float*)d_in[14];
  const float* bn1b  = (const float*)d_in[15];
  const float* bn1m  = (const float*)d_in[16];
  const float* bn1v  = (const float*)d_in[17];
  const float* W1    = (const float*)d_in[18];
  const float* b1    = (const float*)d_in[19];
  const float* bn2g  = (const float*)d_in[20];
  const float* bn2b  = (const float*)d_in[21];
  const float* bn2m  = (const float*)d_in[22];
  const float* bn2v  = (const float*)d_in[23];
  const float* W2    = (const float*)d_in[24];
  const float* b2v   = (const float*)d_in[25];

  char* base = (char*)d_ws;
  size_t off = 0;
  auto alloc = [&](size_t n) { char* p = base + off; off = (off + n + 255) & ~(size_t)255; return p; };

  f16*   WmhS   = (f16*)  alloc((size_t)120 * NKA * 512 * 2);
  f16*   WhS    = (f16*)  alloc((size_t)119 * 4 * NKB * 512 * 2);
  f16*   wmxT   = (f16*)  alloc((size_t)HP * 32 * 2);
  f16*   xe16   = (f16*)  alloc((size_t)TT * NR * 32 * 2);
  f16*   h0S    = (f16*)  alloc((size_t)32 * NKA * 512 * 2);
  f16*   h1S    = (f16*)  alloc((size_t)32 * NKA * 512 * 2);
  f16*   mS     = (f16*)  alloc((size_t)32 * NKB * 512 * 2);
  float* cst    = (float*)alloc((size_t)NR * HP * 4);
  float* selH   = (float*)alloc((size_t)NR * HP * 4);
  int*   sel    = (int*)  alloc((size_t)NR * 4);
  float* inv_wh = (float*)alloc(7600 * 4);
  float* inv_wx = (float*)alloc(7600 * 4);
  float* inv_wmh= (float*)alloc(1900 * 4);
  float* inv_wmx= (float*)alloc(1900 * 4);
  f16*   xqS    = (f16*)  alloc((size_t)16 * NKF * 512 * 2);
  f16*   W1S    = (f16*)  alloc((size_t)24 * NKF * 512 * 2);
  float* z1     = (float*)alloc((size_t)256 * FCN * 4);
  (void)in_sizes; (void)n_in; (void)out_size; (void)ws_size;

  hipLaunchKernelGGL(k_norms, dim3(75), dim3(256), 0, stream,
                     wh, wx, wmh, wmx, gh, gx, gmh, gmx, inv_wh, inv_wx, inv_wmh, inv_wmx);
  hipLaunchKernelGGL(k_wmhS, dim3((1920 * 1920 + 255) / 256), dim3(256), 0, stream,
                     wmh, inv_wmh, WmhS);
  hipLaunchKernelGGL(k_whS, dim3((7600 * 1952 + 255) / 256), dim3(256), 0, stream,
                     wh, wx, bb, inv_wh, inv_wx, WhS);
  hipLaunchKernelGGL(k_wmxT, dim3((HP * 32 + 255) / 256), dim3(256), 0, stream,
                     wmx, inv_wmx, wmxT);
  hipLaunchKernelGGL(k_lens, dim3(1), dim3(256), 0, stream, epix, lx, rx, sel);
  hipLaunchKernelGGL(k_init, dim3((NR * HP + 255) / 256), dim3(256), 0, stream,
                     h0S, h1S, cst);
  hipLaunchKernelGGL(k_xe16, dim3((TT * NR + 255) / 256), dim3(256), 0, stream,
                     totx, epix, embed, xe16);

  for (int t = 0; t < TT; t++) {
    int Mt = (t < TE) ? NR : 256;
    const f16* hin = (t & 1) ? h1S : h0S;
    f16*       ho  = (t & 1) ? h0S : h1S;
    hipLaunchKernelGGL(k_stepA, dim3(30 * (Mt / 64)), dim3(256), 0, stream,
                       hin, WmhS, xe16 + (size_t)t * NR * 32, wmxT, mS);
    hipLaunchKernelGGL(k_stepB, dim3(119 * (Mt / 128)), dim3(256), 0, stream,
                       mS, WhS, cst, ho, selH, sel, t);
  }

  hipLaunchKernelGGL(k_xqS, dim3((256 * 3840 + 255) / 256), dim3(256), 0, stream,
                     selH, bn1g, bn1b, bn1m, bn1v, xqS);
  hipLaunchKernelGGL(k_w1S, dim3((384 * 3840 + 255) / 256), dim3(256), 0, stream, W1, W1S);
  hipLaunchKernelGGL(k_fc1, dim3(24), dim3(256), 0, stream, xqS, W1S, b1, z1);
  hipLaunchKernelGGL(k_fc2, dim3(1), dim3(256), 0, stream,
                     z1, bn2g, bn2b, bn2m, bn2v, W2, b2v, (float*)d_out);
}

// Round 6
// 5610.659 us; speedup vs baseline: 2.3789x; 1.3899x over previous
//
#include <hip/hip_runtime.h>

// ---------------------------------------------------------------------------
// mLSTM epitope/antigen model, MI355X fp16-MFMA, round 6.
//
// R6 vs R5 (7.80 ms):
//  - BRANCH-FREE steady-state K-loops. R5 issued prefetch loads under
//    `if (base+k < NK)` -> outstanding-load count opaque -> compiler forced
//    s_waitcnt vmcnt(0) every chunk -> one full memory latency per chunk
//    (~750cy x 61 = observed ~18us/kernel). Now: unconditional prefetch in
//    the steady loop, tail chunks peeled. Precise vmcnt -> pipelined loads.
//  - XCD-stable block mapping (blockIdx%8 == colq%8, invariant over t):
//    WhS slices (~3.7 MB/XCD) stay L2-resident across all 153 steps.
// ---------------------------------------------------------------------------

typedef _Float16 f16;
typedef _Float16 half8 __attribute__((ext_vector_type(8)));
typedef float f32x4 __attribute__((ext_vector_type(4)));

#define H_    1900
#define HP    1920
#define NKA   60     // K-chunks for h/WmhS (1920/32)
#define NKB   61     // K-chunks for m/WhS (1952/32)
#define NKF   120    // K-chunks for fc1 (3840/32)
#define NR    512
#define TT    153
#define TE    25
#define EMB_  10
#define FCN   384

__device__ __forceinline__ float sigm(float x) {
  float p = __expf(-fabsf(x));
  float r = 1.f / (1.f + p);
  return x >= 0.f ? r : 1.f - r;
}
__device__ __forceinline__ float tanh_(float x) {
  float p = __expf(-2.f * fabsf(x));
  float r = (1.f - p) / (1.f + p);
  return x >= 0.f ? r : -r;
}

// ---------------- prep ----------------

__global__ void k_norms(const float* __restrict__ wh, const float* __restrict__ wx,
                        const float* __restrict__ wmh, const float* __restrict__ wmx,
                        const float* __restrict__ gh, const float* __restrict__ gx,
                        const float* __restrict__ gmh, const float* __restrict__ gmx,
                        float* __restrict__ inv_wh, float* __restrict__ inv_wx,
                        float* __restrict__ inv_wmh, float* __restrict__ inv_wmx) {
  int tid = blockIdx.x * 256 + threadIdx.x;
  if (tid < 7600) {
    float s = 0.f;
    for (int k = 0; k < H_; k++) { float v = wh[(size_t)k * 7600 + tid]; s += v * v; }
    inv_wh[tid] = gh[tid] * rsqrtf(fmaxf(s, 1e-12f));
  } else if (tid < 15200) {
    int n = tid - 7600; float s = 0.f;
    for (int e = 0; e < EMB_; e++) { float v = wx[(size_t)e * 7600 + n]; s += v * v; }
    inv_wx[n] = gx[n] * rsqrtf(fmaxf(s, 1e-12f));
  } else if (tid < 17100) {
    int n = tid - 15200; float s = 0.f;
    for (int k = 0; k < H_; k++) { float v = wmh[(size_t)k * H_ + n]; s += v * v; }
    inv_wmh[n] = gmh[n] * rsqrtf(fmaxf(s, 1e-12f));
  } else if (tid < 19000) {
    int n = tid - 17100; float s = 0.f;
    for (int e = 0; e < EMB_; e++) { float v = wmx[(size_t)e * H_ + n]; s += v * v; }
    inv_wmx[n] = gmx[n] * rsqrtf(fmaxf(s, 1e-12f));
  }
}

// WmhS fragment-swizzled: group (c,kb): element (n=16c+nl, k=32kb+kl)
__global__ void k_wmhS(const float* __restrict__ wmh, const float* __restrict__ inv,
                       f16* __restrict__ WmhS) {
  int i = blockIdx.x * 256 + threadIdx.x;
  if (i >= 1920 * 1920) return;
  int n = i % 1920, k = i / 1920;
  float v = (n < H_ && k < H_) ? wmh[(size_t)k * H_ + n] * inv[n] : 0.f;
  int c = n >> 4, nl = n & 15, kb = k >> 5, kl = k & 31;
  WmhS[(((size_t)c * NKA + kb) * 512) + (nl + 16 * (kl >> 3)) * 8 + (kl & 7)] = (f16)v;
}

// WhS fragment-swizzled, gate-grouped: group (q*4+g, kb); K-ext rows carry wx/b
__global__ void k_whS(const float* __restrict__ wh, const float* __restrict__ wx,
                      const float* __restrict__ bias,
                      const float* __restrict__ inv_wh, const float* __restrict__ inv_wx,
                      f16* __restrict__ WhS) {
  int i = blockIdx.x * 256 + threadIdx.x;
  if (i >= 7600 * 1952) return;
  int col = i % 7600, k = i / 7600;
  float v = 0.f;
  if (k < H_)                        v = wh[(size_t)k * 7600 + col] * inv_wh[col];
  else if (k >= HP && k < HP + EMB_) v = wx[(size_t)(k - HP) * 7600 + col] * inv_wx[col];
  else if (k == HP + EMB_)           v = bias[col];
  int g = col / H_, n = col % H_;
  int q = n >> 4, nl = n & 15, kb = k >> 5, kl = k & 31;
  WhS[(((size_t)(q * 4 + g) * NKB + kb) * 512) + (nl + 16 * (kl >> 3)) * 8 + (kl & 7)] = (f16)v;
}

__global__ void k_wmxT(const float* __restrict__ wmx, const float* __restrict__ inv_wmx,
                       f16* __restrict__ wmxT) {
  int i = blockIdx.x * 256 + threadIdx.x;
  if (i >= HP * 32) return;
  int n = i >> 5, k = i & 31;
  float v = (k < EMB_ && n < H_) ? wmx[(size_t)k * H_ + n] * inv_wmx[n] : 0.f;
  wmxT[i] = (f16)v;
}

__global__ void k_lens(const int* __restrict__ ex, const int* __restrict__ lx,
                       const int* __restrict__ rx, int* __restrict__ sel) {
  int s = threadIdx.x;
  int el = 0; for (int i = 0; i < 25; i++) el += (ex[s * 25 + i] != 26);
  int ll = 0; for (int i = 0; i < 64; i++) ll += (lx[s * 64 + i] != 26);
  int rl = 0; for (int i = 0; i < 64; i++) rl += (rx[s * 64 + i] != 26);
  ll = ll < 1 ? 1 : ll;  rl = rl < 1 ? 1 : rl;
  int tl = el + ll + rl;
  int ti = tl - 1; ti = ti < 0 ? 0 : (ti > 152 ? 152 : ti);
  int ei = el - 1; ei = ei < 0 ? 0 : (ei > 24 ? 24 : ei);
  sel[s] = ti; sel[256 + s] = ei;
}

__global__ void k_init(f16* __restrict__ h0, f16* __restrict__ h1, float* __restrict__ c) {
  int i = blockIdx.x * 256 + threadIdx.x;
  if (i < NR * HP) { h0[i] = (f16)0.f; h1[i] = (f16)0.f; c[i] = 0.f; }
}

// xe16[t][row][32]: cols 0..9 = embed[token], col 10 = 1.0 (bias), rest 0
__global__ void k_xe16(const int* __restrict__ totx, const int* __restrict__ epix,
                       const float* __restrict__ embed, f16* __restrict__ xe16) {
  int i = blockIdx.x * blockDim.x + threadIdx.x;
  if (i >= TT * NR) return;
  int t = i / NR, r = i % NR;
  int tok = -1;
  if (r < 256) tok = totx[r * TT + t];
  else if (t < TE) tok = epix[(r - 256) * TE + t];
  f16* o = xe16 + (size_t)i * 32;
  #pragma unroll
  for (int e = 0; e < EMB_; e++) o[e] = (f16)(tok >= 0 ? embed[tok * EMB_ + e] : 0.f);
  o[10] = (f16)1.f;
  #pragma unroll
  for (int e = 11; e < 32; e++) o[e] = (f16)0.f;
}

// ---------------- recurrence ----------------

// Phase A: wave = 16 rows x 64 cols; contiguous 1KB fragment loads;
// branch-free pipeline. Block id: x=bi&7 -> ct%8 (XCD-stable).
__global__ __launch_bounds__(256)
void k_stepA(const f16* __restrict__ hS, const f16* __restrict__ WmhS,
             const f16* __restrict__ xe16_t, const f16* __restrict__ wmxT,
             f16* __restrict__ mS, int rgc) {
  const int lane = threadIdx.x & 63, wid = threadIdx.x >> 6;
  const int bi = blockIdx.x;
  const int x = bi & 7, mm = bi >> 3;
  const int rg = mm % rgc, chi = mm / rgc;
  const int ct = chi * 8 + x;
  if (ct >= 30) return;
  const int rtile = rg * 4 + wid;
  const int r0 = rtile * 16;
  const int l16 = lane & 15, l4 = lane >> 4;

  const f16* Abase = hS   + (size_t)rtile * NKA * 512 + lane * 8;
  const f16* Bbase = WmhS + (size_t)(ct * 4) * NKA * 512 + lane * 8;

  // xm = xe16 @ wmxT (once per wave)
  f32x4 xm[4];
  {
    half8 xa = *(const half8*)(xe16_t + (size_t)(r0 + l16) * 32 + l4 * 8);
    #pragma unroll
    for (int cb = 0; cb < 4; cb++) {
      half8 xb = *(const half8*)(wmxT + (size_t)(ct * 64 + cb * 16 + l16) * 32 + l4 * 8);
      f32x4 z = {0.f, 0.f, 0.f, 0.f};
      xm[cb] = __builtin_amdgcn_mfma_f32_16x16x32_f16(xa, xb, z, 0, 0, 0);
    }
  }

  half8 fa0, fa1, fa2, fa3;
  half8 fb0[4], fb1[4], fb2[4], fb3[4];
  f32x4 acc[4];
  #pragma unroll
  for (int cb = 0; cb < 4; cb++) { f32x4 z = {0.f, 0.f, 0.f, 0.f}; acc[cb] = z; }

#define LDA_A(d, kb)  d = *(const half8*)(Abase + (size_t)(kb) * 512)
#define LDB_A(d, kb)  { _Pragma("unroll") for (int cb = 0; cb < 4; cb++) \
    d[cb] = *(const half8*)(Bbase + ((size_t)cb * NKA + (kb)) * 512); }
#define MMA_A(fa, fb) { _Pragma("unroll") for (int cb = 0; cb < 4; cb++) \
    acc[cb] = __builtin_amdgcn_mfma_f32_16x16x32_f16(fa, fb[cb], acc[cb], 0, 0, 0); }

  LDA_A(fa0, 0); LDB_A(fb0, 0);
  LDA_A(fa1, 1); LDB_A(fb1, 1);
  LDA_A(fa2, 2); LDB_A(fb2, 2);
  // steady state: NO conditionals. base = 0..52, consumes 0..55, loads <= 58.
  for (int base = 0; base < 56; base += 4) {
    LDA_A(fa3, base + 3); LDB_A(fb3, base + 3);
    MMA_A(fa0, fb0);
    LDA_A(fa0, base + 4); LDB_A(fb0, base + 4);
    MMA_A(fa1, fb1);
    LDA_A(fa1, base + 5); LDB_A(fb1, base + 5);
    MMA_A(fa2, fb2);
    LDA_A(fa2, base + 6); LDB_A(fb2, base + 6);
    MMA_A(fa3, fb3);
  }
  // tail: bufs hold 56,57,58; chunk 59 remains
  LDA_A(fa3, 59); LDB_A(fb3, 59);
  MMA_A(fa0, fb0);   // 56
  MMA_A(fa1, fb1);   // 57
  MMA_A(fa2, fb2);   // 58
  MMA_A(fa3, fb3);   // 59
#undef LDA_A
#undef LDB_A
#undef MMA_A

  // epilogue: m = hm * xm, written in stepB's A-fragment order
  const int q4 = lane >> 4, c16 = lane & 15;
  #pragma unroll
  for (int cb = 0; cb < 4; cb++) {
    int kb = ct * 2 + (cb >> 1);
    int klane = (cb & 1) * 16 + c16;
    int lf = (klane >> 3) * 16;
    int sub = c16 & 7;
    f16* dst = mS + ((size_t)rtile * NKB + kb) * 512 + sub;
    #pragma unroll
    for (int q = 0; q < 4; q++) {
      int rl = q4 * 4 + q;
      dst[(rl + lf) * 8] = (f16)(acc[cb][q] * xm[cb][q]);
    }
  }
  if (ct == 0) {  // K-extension chunk 60 = xe16 row (contiguous copy)
    f16* dst = mS + ((size_t)rtile * NKB + 60) * 512 + lane * 8;
    *(half8*)dst = *(const half8*)(xe16_t + (size_t)(r0 + l16) * 32 + l4 * 8);
  }
}

// Phase B: wave = 32 rows x (16 cols x 4 gates); branch-free pipeline.
// Block id: x=bi&7 -> colq%8 (XCD-stable; WhS slice stays in that XCD's L2).
__global__ __launch_bounds__(256)
void k_stepB(const f16* __restrict__ mS, const f16* __restrict__ WhS,
             float* __restrict__ c, f16* __restrict__ houtS,
             float* __restrict__ selH, const int* __restrict__ sel, int t, int rgc) {
  const int lane = threadIdx.x & 63, wid = threadIdx.x >> 6;
  const int bi = blockIdx.x;
  const int x = bi & 7, mm = bi >> 3;
  const int rg = mm % rgc, chi = mm / rgc;
  const int colq = chi * 8 + x;
  if (colq >= 119) return;
  const int rt0 = (rg * 4 + wid) * 2;
  const int r0 = rt0 * 16;

  const f16* Abase = mS  + (size_t)rt0 * NKB * 512 + lane * 8;
  const f16* Bbase = WhS + (size_t)(colq * 4) * NKB * 512 + lane * 8;

  half8 fa0[2], fa1[2], fa2[2], fa3[2];
  half8 fb0[4], fb1[4], fb2[4], fb3[4];
  f32x4 acc[2][4];
  #pragma unroll
  for (int a = 0; a < 2; a++)
    #pragma unroll
    for (int b = 0; b < 4; b++) { f32x4 z = {0.f, 0.f, 0.f, 0.f}; acc[a][b] = z; }

#define LDA_B(d, kb)  { _Pragma("unroll") for (int rf = 0; rf < 2; rf++) \
    d[rf] = *(const half8*)(Abase + ((size_t)rf * NKB + (kb)) * 512); }
#define LDB_B(d, kb)  { _Pragma("unroll") for (int gg = 0; gg < 4; gg++) \
    d[gg] = *(const half8*)(Bbase + ((size_t)gg * NKB + (kb)) * 512); }
#define MMA_B(fa, fb) { _Pragma("unroll") for (int rf = 0; rf < 2; rf++) \
    { _Pragma("unroll") for (int gg = 0; gg < 4; gg++) \
      acc[rf][gg] = __builtin_amdgcn_mfma_f32_16x16x32_f16(fa[rf], fb[gg], acc[rf][gg], 0, 0, 0); } }

  LDA_B(fa0, 0); LDB_B(fb0, 0);
  LDA_B(fa1, 1); LDB_B(fb1, 1);
  LDA_B(fa2, 2); LDB_B(fb2, 2);
  // steady state: NO conditionals. base = 0..52, consumes 0..55, loads <= 58.
  for (int base = 0; base < 56; base += 4) {
    LDA_B(fa3, base + 3); LDB_B(fb3, base + 3);
    MMA_B(fa0, fb0);
    LDA_B(fa0, base + 4); LDB_B(fb0, base + 4);
    MMA_B(fa1, fb1);
    LDA_B(fa1, base + 5); LDB_B(fb1, base + 5);
    MMA_B(fa2, fb2);
    LDA_B(fa2, base + 6); LDB_B(fb2, base + 6);
    MMA_B(fa3, fb3);
  }
  // tail: bufs hold 56,57,58; chunks 59,60 remain
  LDA_B(fa3, 59); LDB_B(fb3, 59);
  MMA_B(fa0, fb0);   // 56
  LDA_B(fa0, 60); LDB_B(fb0, 60);
  MMA_B(fa1, fb1);   // 57
  MMA_B(fa2, fb2);   // 58
  MMA_B(fa3, fb3);   // 59
  MMA_B(fa0, fb0);   // 60
#undef LDA_B
#undef LDB_B
#undef MMA_B

  const int q4 = lane >> 4, c16 = lane & 15;
  const int j = colq * 16 + c16;
  const bool valid = j < H_;
  const int kbh = colq >> 1;
  const int lfh = ((((colq & 1) * 16 + c16) >> 3)) * 16;
  const int subh = c16 & 7;
  #pragma unroll
  for (int rf = 0; rf < 2; rf++) {
    f16* hdst = houtS + ((size_t)(rt0 + rf) * NKA + kbh) * 512 + subh;
    #pragma unroll
    for (int q = 0; q < 4; q++) {
      int rl = q4 * 4 + q;
      int row = r0 + rf * 16 + rl;
      if (valid) {
        size_t idx = (size_t)row * HP + j;
        float cold = c[idx];
        float iz = acc[rf][0][q], fz = acc[rf][1][q];
        float oz = acc[rf][2][q], uz = acc[rf][3][q];
        float cn = sigm(fz) * cold + sigm(iz) * tanh_(uz);
        float hv = sigm(oz) * tanh_(cn);
        c[idx] = cn;
        hdst[(rl + lfh) * 8] = (f16)hv;
        if (t == sel[row]) selH[idx] = hv;
      }
    }
  }
}

// ---------------- classifier ----------------

__global__ void k_xqS(const float* __restrict__ selH, const float* __restrict__ g1,
                      const float* __restrict__ be1, const float* __restrict__ mu1,
                      const float* __restrict__ var1, f16* __restrict__ xqS) {
  int i = blockIdx.x * 256 + threadIdx.x;
  if (i >= 256 * 3840) return;
  int k = i % 3840, s = i / 3840;
  float v = 0.f; bool have = false;
  if (k < H_)            { v = selH[(size_t)s * HP + k]; have = true; }
  else if (k < 2 * H_)   { v = selH[(size_t)(256 + s) * HP + (k - H_)]; have = true; }
  float q = 0.f;
  if (have) {
    float lr = v < 0.f ? 0.3f * v : v;
    q = (lr - mu1[k]) * rsqrtf(var1[k] + 1e-3f) * g1[k] + be1[k];
  }
  int rtile = s >> 4, sl = s & 15, kb = k >> 5, kl = k & 31;
  xqS[(((size_t)rtile * NKF + kb) * 512) + (sl + 16 * (kl >> 3)) * 8 + (kl & 7)] = (f16)q;
}

__global__ void k_w1S(const float* __restrict__ W1, f16* __restrict__ W1S) {
  int i = blockIdx.x * 256 + threadIdx.x;
  if (i >= 384 * 3840) return;
  int col = i % 384, k = i / 384;
  float v = (col < 380 && k < 2 * H_) ? W1[(size_t)k * 380 + col] : 0.f;
  int cg = col >> 4, nl = col & 15, kb = k >> 5, kl = k & 31;
  W1S[(((size_t)cg * NKF + kb) * 512) + (nl + 16 * (kl >> 3)) * 8 + (kl & 7)] = (f16)v;
}

// fc1: wave = 16 rows x 64 cols, K=3840 (120 chunks), branch-free pipeline
__global__ __launch_bounds__(256)
void k_fc1(const f16* __restrict__ xqS, const f16* __restrict__ W1S,
           const float* __restrict__ b1, float* __restrict__ z1) {
  const int lane = threadIdx.x & 63, wid = threadIdx.x >> 6;
  const int ct = blockIdx.x % 6, rg = blockIdx.x / 6;
  const int rtile = rg * 4 + wid;
  const int r0 = rtile * 16;

  const f16* Abase = xqS + (size_t)rtile * NKF * 512 + lane * 8;
  const f16* Bbase = W1S + (size_t)(ct * 4) * NKF * 512 + lane * 8;

  half8 fa0, fa1, fa2, fa3;
  half8 fb0[4], fb1[4], fb2[4], fb3[4];
  f32x4 acc[4];
  #pragma unroll
  for (int cb = 0; cb < 4; cb++) { f32x4 z = {0.f, 0.f, 0.f, 0.f}; acc[cb] = z; }

#define LDA_F(d, kb)  d = *(const half8*)(Abase + (size_t)(kb) * 512)
#define LDB_F(d, kb)  { _Pragma("unroll") for (int cb = 0; cb < 4; cb++) \
    d[cb] = *(const half8*)(Bbase + ((size_t)cb * NKF + (kb)) * 512); }
#define MMA_F(fa, fb) { _Pragma("unroll") for (int cb = 0; cb < 4; cb++) \
    acc[cb] = __builtin_amdgcn_mfma_f32_16x16x32_f16(fa, fb[cb], acc[cb], 0, 0, 0); }

  LDA_F(fa0, 0); LDB_F(fb0, 0);
  LDA_F(fa1, 1); LDB_F(fb1, 1);
  LDA_F(fa2, 2); LDB_F(fb2, 2);
  // steady: base = 0..112, consumes 0..115, loads <= 118
  for (int base = 0; base < 116; base += 4) {
    LDA_F(fa3, base + 3); LDB_F(fb3, base + 3);
    MMA_F(fa0, fb0);
    LDA_F(fa0, base + 4); LDB_F(fb0, base + 4);
    MMA_F(fa1, fb1);
    LDA_F(fa1, base + 5); LDB_F(fb1, base + 5);
    MMA_F(fa2, fb2);
    LDA_F(fa2, base + 6); LDB_F(fb2, base + 6);
    MMA_F(fa3, fb3);
  }
  LDA_F(fa3, 119); LDB_F(fb3, 119);
  MMA_F(fa0, fb0);   // 116
  MMA_F(fa1, fb1);   // 117
  MMA_F(fa2, fb2);   // 118
  MMA_F(fa3, fb3);   // 119
#undef LDA_F
#undef LDB_F
#undef MMA_F

  const int q4 = lane >> 4, c16 = lane & 15;
  #pragma unroll
  for (int cb = 0; cb < 4; cb++)
    #pragma unroll
    for (int q = 0; q < 4; q++) {
      int row = r0 + q4 * 4 + q;
      int col = ct * 64 + cb * 16 + c16;
      float bias = (col < 380) ? b1[col] : 0.f;
      z1[(size_t)row * FCN + col] = acc[cb][q] + bias;
    }
}

__global__ void k_fc2(const float* __restrict__ z1, const float* __restrict__ g2,
                      const float* __restrict__ be2, const float* __restrict__ mu2,
                      const float* __restrict__ var2, const float* __restrict__ W2,
                      const float* __restrict__ b2, float* __restrict__ out) {
  int s = threadIdx.x;
  float a = 0.f;
  for (int jj = 0; jj < 380; jj++) {
    float v = z1[(size_t)s * FCN + jj];
    float lr = v < 0.f ? 0.3f * v : v;
    float q = (lr - mu2[jj]) * rsqrtf(var2[jj] + 1e-3f) * g2[jj] + be2[jj];
    a += q * W2[jj];
  }
  out[s] = a + b2[0];
}

// ---------------- host ----------------

extern "C" void kernel_launch(void* const* d_in, const int* in_sizes, int n_in,
                              void* d_out, int out_size, void* d_ws, size_t ws_size,
                              hipStream_t stream) {
  const int*   epix  = (const int*)d_in[0];
  const int*   lx    = (const int*)d_in[1];
  const int*   rx    = (const int*)d_in[2];
  const int*   totx  = (const int*)d_in[3];
  const float* embed = (const float*)d_in[4];
  const float* wx    = (const float*)d_in[5];
  const float* wh    = (const float*)d_in[6];
  const float* wmx   = (const float*)d_in[7];
  const float* wmh   = (const float*)d_in[8];
  const float* bb    = (const float*)d_in[9];
  const float* gx    = (const float*)d_in[10];
  const float* gh    = (const float*)d_in[11];
  const float* gmx   = (const float*)d_in[12];
  const float* gmh   = (const float*)d_in[13];
  const float* bn1g  = (const float*)d_in[14];
  const float* bn1b  = (const float*)d_in[15];
  const float* bn1m  = (const float*)d_in[16];
  const float* bn1v  = (const float*)d_in[17];
  const float* W1    = (const float*)d_in[18];
  const float* b1    = (const float*)d_in[19];
  const float* bn2g  = (const float*)d_in[20];
  const float* bn2b  = (const float*)d_in[21];
  const float* bn2m  = (const float*)d_in[22];
  const float* bn2v  = (const float*)d_in[23];
  const float* W2    = (const float*)d_in[24];
  const float* b2v   = (const float*)d_in[25];

  char* base = (char*)d_ws;
  size_t off = 0;
  auto alloc = [&](size_t n) { char* p = base + off; off = (off + n + 255) & ~(size_t)255; return p; };

  f16*   WmhS   = (f16*)  alloc((size_t)120 * NKA * 512 * 2);
  f16*   WhS    = (f16*)  alloc((size_t)119 * 4 * NKB * 512 * 2);
  f16*   wmxT   = (f16*)  alloc((size_t)HP * 32 * 2);
  f16*   xe16   = (f16*)  alloc((size_t)TT * NR * 32 * 2);
  f16*   h0S    = (f16*)  alloc((size_t)32 * NKA * 512 * 2);
  f16*   h1S    = (f16*)  alloc((size_t)32 * NKA * 512 * 2);
  f16*   mS     = (f16*)  alloc((size_t)32 * NKB * 512 * 2);
  float* cst    = (float*)alloc((size_t)NR * HP * 4);
  float* selH   = (float*)alloc((size_t)NR * HP * 4);
  int*   sel    = (int*)  alloc((size_t)NR * 4);
  float* inv_wh = (float*)alloc(7600 * 4);
  float* inv_wx = (float*)alloc(7600 * 4);
  float* inv_wmh= (float*)alloc(1900 * 4);
  float* inv_wmx= (float*)alloc(1900 * 4);
  f16*   xqS    = (f16*)  alloc((size_t)16 * NKF * 512 * 2);
  f16*   W1S    = (f16*)  alloc((size_t)24 * NKF * 512 * 2);
  float* z1     = (float*)alloc((size_t)256 * FCN * 4);
  (void)in_sizes; (void)n_in; (void)out_size; (void)ws_size;

  hipLaunchKernelGGL(k_norms, dim3(75), dim3(256), 0, stream,
                     wh, wx, wmh, wmx, gh, gx, gmh, gmx, inv_wh, inv_wx, inv_wmh, inv_wmx);
  hipLaunchKernelGGL(k_wmhS, dim3((1920 * 1920 + 255) / 256), dim3(256), 0, stream,
                     wmh, inv_wmh, WmhS);
  hipLaunchKernelGGL(k_whS, dim3((7600 * 1952 + 255) / 256), dim3(256), 0, stream,
                     wh, wx, bb, inv_wh, inv_wx, WhS);
  hipLaunchKernelGGL(k_wmxT, dim3((HP * 32 + 255) / 256), dim3(256), 0, stream,
                     wmx, inv_wmx, wmxT);
  hipLaunchKernelGGL(k_lens, dim3(1), dim3(256), 0, stream, epix, lx, rx, sel);
  hipLaunchKernelGGL(k_init, dim3((NR * HP + 255) / 256), dim3(256), 0, stream,
                     h0S, h1S, cst);
  hipLaunchKernelGGL(k_xe16, dim3((TT * NR + 255) / 256), dim3(256), 0, stream,
                     totx, epix, embed, xe16);

  for (int t = 0; t < TT; t++) {
    int Mt = (t < TE) ? NR : 256;
    const f16* hin = (t & 1) ? h1S : h0S;
    f16*       ho  = (t & 1) ? h0S : h1S;
    int rgcA = Mt / 64;   // blocks of 64 rows
    int rgcB = Mt / 128;  // blocks of 128 rows
    hipLaunchKernelGGL(k_stepA, dim3(8 * rgcA * 4), dim3(256), 0, stream,
                       hin, WmhS, xe16 + (size_t)t * NR * 32, wmxT, mS, rgcA);
    hipLaunchKernelGGL(k_stepB, dim3(8 * rgcB * 15), dim3(256), 0, stream,
                       mS, WhS, cst, ho, selH, sel, t, rgcB);
  }

  hipLaunchKernelGGL(k_xqS, dim3((256 * 3840 + 255) / 256), dim3(256), 0, stream,
                     selH, bn1g, bn1b, bn1m, bn1v, xqS);
  hipLaunchKernelGGL(k_w1S, dim3((384 * 3840 + 255) / 256), dim3(256), 0, stream, W1, W1S);
  hipLaunchKernelGGL(k_fc1, dim3(24), dim3(256), 0, stream, xqS, W1S, b1, z1);
  hipLaunchKernelGGL(k_fc2, dim3(1), dim3(256), 0, stream,
                     z1, bn2g, bn2b, bn2m, bn2v, W2, b2v, (float*)d_out);
}